// Round 11
// baseline (88.104 us; speedup 1.0000x reference)
//
#include <hip/hip_runtime.h>

// IDW, POWER=2.0 -> w = 1/d2 (sqrt cancels). out = sum(w*v)/sum(w).
// B=2, P=131072, S=512.
// R11: best config (GPT=2 + SMEM station path, R8) + explicit 1-iter SMEM
//   prefetch rotation (~290cyc compute/iter hides ~100-200cyc scalar-cache
//   latency regardless of TLP) + s_load_dwordx8 chunks (3 SMEM inst / 8
//   stations) + rcp epilogue. Floor recalibrated: m07 shows sustained VALU
//   issue = 0.65 of peak -> 17cyc/station-point math floors at ~22us, not
//   14.5. R8's 30us gap is per-chunk fetch bubbles -> explicit prefetch.
// Quad math: 4-way rcp combine (1 v_rcp / 4 stations), EPS2 folded into the
// d2 fma chain (exact at d2==0: w -> 1/EPS^2 like ref).

#define BLOCK 256
#define GPT 2

typedef float v8f __attribute__((ext_vector_type(8)));
typedef const __attribute__((address_space(4))) v8f k_v8f;

__global__ __launch_bounds__(BLOCK) void idw_kernel(
    const float* __restrict__ station_coords,  // (B, S, 2)
    const float* __restrict__ station_values,  // (B, S)
    const float* __restrict__ grid_points,     // (B, P, 2)
    float* __restrict__ out,                   // (B, P)
    int P, int S) {

    const int b = blockIdx.y;

    // Wave-uniform station data -> scalar pipe (s_load_dwordx8).
    // coords: 4 stations per v8f; values: 8 per v8f.
    k_v8f* sc8 = (k_v8f*)(station_coords + (size_t)b * S * 2);
    k_v8f* sv8 = (k_v8f*)(station_values + (size_t)b * S);

    const int tid = blockIdx.x * BLOCK + threadIdx.x;
    const float4 g01 = ((const float4*)grid_points)[(size_t)b * (P / 2) + tid];
    const float gx0 = g01.x, gy0 = g01.y, gx1 = g01.z, gy1 = g01.w;

    constexpr float EPS  = 1.1920928955078125e-07f;
    constexpr float EPS2 = EPS * EPS;

    float wsum0 = 0.0f, vsum0 = 0.0f;
    float wsum1 = 0.0f, vsum1 = 0.0f;

    // 4 stations vs one point: 30 plain VALU + 1 rcp.
    // cq = x0 y0 x1 y1 x2 y2 x3 y3 ; v0..v3 scalar values.
    auto quad = [&](float gx, float gy, float& ws, float& vs,
                    v8f cq, float v0, float v1, float v2, float v3) {
        const float dxa = gx - cq[0], dya = gy - cq[1];
        const float a = fmaf(dxa, dxa, fmaf(dya, dya, EPS2));
        const float dxb = gx - cq[2], dyb = gy - cq[3];
        const float bq = fmaf(dxb, dxb, fmaf(dyb, dyb, EPS2));
        const float dxc = gx - cq[4], dyc = gy - cq[5];
        const float c = fmaf(dxc, dxc, fmaf(dyc, dyc, EPS2));
        const float dxd = gx - cq[6], dyd = gy - cq[7];
        const float d = fmaf(dxd, dxd, fmaf(dyd, dyd, EPS2));
        const float pab = a * bq, pcd = c * d;
        const float sab = a + bq, scd = c + d;
        const float nab = fmaf(v1, a, v0 * bq);  // vB*a + vA*b
        const float ncd = fmaf(v3, c, v2 * d);   // vD*c + vC*d
        const float r = __builtin_amdgcn_rcpf(pab * pcd);
        ws = fmaf(fmaf(sab, pcd, scd * pab), r, ws);
        vs = fmaf(fmaf(nab, pcd, ncd * pab), r, vs);
    };

    // 8 stations per iteration; explicit prefetch rotation (1 iter deep).
    v8f cA = sc8[0];   // stations 0..3 coords
    v8f cB = sc8[1];   // stations 4..7 coords
    v8f vv = sv8[0];   // values 0..7

#pragma unroll 4
    for (int k = 0; k < 512 / 8 - 1; ++k) {
        const v8f nA = sc8[2 * k + 2];
        const v8f nB = sc8[2 * k + 3];
        const v8f nv = sv8[k + 1];
        quad(gx0, gy0, wsum0, vsum0, cA, vv[0], vv[1], vv[2], vv[3]);
        quad(gx1, gy1, wsum1, vsum1, cA, vv[0], vv[1], vv[2], vv[3]);
        quad(gx0, gy0, wsum0, vsum0, cB, vv[4], vv[5], vv[6], vv[7]);
        quad(gx1, gy1, wsum1, vsum1, cB, vv[4], vv[5], vv[6], vv[7]);
        cA = nA; cB = nB; vv = nv;
    }
    quad(gx0, gy0, wsum0, vsum0, cA, vv[0], vv[1], vv[2], vv[3]);
    quad(gx1, gy1, wsum1, vsum1, cA, vv[0], vv[1], vv[2], vv[3]);
    quad(gx0, gy0, wsum0, vsum0, cB, vv[4], vv[5], vv[6], vv[7]);
    quad(gx1, gy1, wsum1, vsum1, cB, vv[4], vv[5], vv[6], vv[7]);

    const float r0 = vsum0 * __builtin_amdgcn_rcpf(wsum0);
    const float r1 = vsum1 * __builtin_amdgcn_rcpf(wsum1);
    ((float2*)out)[(size_t)b * (P / 2) + tid] = make_float2(r0, r1);
}

extern "C" void kernel_launch(void* const* d_in, const int* in_sizes, int n_in,
                              void* d_out, int out_size, void* d_ws, size_t ws_size,
                              hipStream_t stream) {
    const float* station_coords = (const float*)d_in[0];
    const float* station_values = (const float*)d_in[1];
    const float* grid_points    = (const float*)d_in[2];
    float* out = (float*)d_out;

    const int B = 2;
    const int S = in_sizes[1] / B;   // 512
    const int P = out_size / B;      // 131072

    dim3 grid(P / (BLOCK * GPT), B);  // 256 x 2 = 512 blocks, 2/CU, 2 w/SIMD
    dim3 block(BLOCK);
    idw_kernel<<<grid, block, 0, stream>>>(station_coords, station_values,
                                           grid_points, out, P, S);
}